// Round 7
// baseline (28.214 us; speedup 1.0000x reference)
//
#include <hip/hip_runtime.h>

#define NB 8
#define NI 16
#define NO 16
#define ND 512
#define ROWS 256                     // output rows per block (half image)
#define RT   (ND / ROWS)             // 2 tiles per (b,o)

typedef float f32x4 __attribute__((ext_vector_type(4)));

// Fused kernel, grid = 128 (b,o) x 2 halves = 256 blocks (exactly 1 per CU).
// Each block: prologue computes full colv/rw/dg (512-wide) + y4/y5, then
// streams a contiguous 512 KB (256 rows x 512 cols) ascending write:
//   out[b,o,r,c] = y2[r]+y5+bias[o] + y3[c] + (r==c)*(y1[r]+y4)
__global__ __launch_bounds__(256) void leq_fused(
    const float* __restrict__ x, const float* __restrict__ weight,
    const float* __restrict__ bias, f32x4* __restrict__ out)
{
    const int blk  = blockIdx.x;         // 0..255
    const int half_img = blk & (RT - 1); // which 256-row half
    const int bo   = blk >> 1;           // 0..127
    const int b    = bo >> 4;
    const int o    = bo & 15;
    const int t    = threadIdx.x;        // 0..255

    __shared__ __align__(16) float colvS[ND];   // y3 per c
    __shared__ __align__(16) float rwS[ND];     // y2[d]+y5+bias (full)
    __shared__ __align__(16) float dgS[ND];     // y1[d]+y4      (full)
    __shared__ __align__(16) float part1[ND];   // odd-i partials
    __shared__ __align__(16) float part2[ND];
    __shared__ __align__(16) float part3[ND];
    __shared__ float red4[4], red5[4];

    const float* wbase = weight + o * (5 * NI);
    const float* xb    = x + b * (NI * ND);
    const float  bia   = bias[o];

    const int half = t >> 7;             // 0: even i, 1: odd i
    const int fq   = t & 127;            // float4 index -> d in [4fq, 4fq+4)

    f32x4 a1 = {0,0,0,0}, a2 = {0,0,0,0}, a3 = {0,0,0,0};
    float p4 = 0.f, p5 = 0.f;

    #pragma unroll
    for (int i2 = 0; i2 < NI / 2; ++i2) {
        const int   i  = i2 * 2 + half;
        const float w0 = wbase[0 * NI + i];
        const float w1 = wbase[1 * NI + i];
        const float w2 = wbase[2 * NI + i];
        const float w3 = wbase[3 * NI + i];
        const float w4 = wbase[4 * NI + i];
        const f32x4 xv = reinterpret_cast<const f32x4*>(xb + i * ND)[fq];
        a1 += w0 * xv;
        a2 += w1 * xv;
        a3 += w2 * xv;
        const float xs = xv.x + xv.y + xv.z + xv.w;
        p4 += w3 * xs; p5 += w4 * xs;
    }

    if (half) {
        reinterpret_cast<f32x4*>(part1)[fq] = a1;
        reinterpret_cast<f32x4*>(part2)[fq] = a2;
        reinterpret_cast<f32x4*>(part3)[fq] = a3;
    }

    // p4/p5: wave shuffle reduce, then cross-wave via LDS
    #pragma unroll
    for (int off = 32; off > 0; off >>= 1) {
        p4 += __shfl_down(p4, off, 64);
        p5 += __shfl_down(p5, off, 64);
    }
    const int wave = t >> 6, lane = t & 63;
    if (lane == 0) { red4[wave] = p4; red5[wave] = p5; }
    __syncthreads();

    const float y4   = red4[0] + red4[1] + red4[2] + red4[3];
    const float y5   = red5[0] + red5[1] + red5[2] + red5[3];
    const float base = y5 + bia;

    if (half == 0) {
        const f32x4 o1 = reinterpret_cast<const f32x4*>(part1)[fq];
        const f32x4 o2 = reinterpret_cast<const f32x4*>(part2)[fq];
        const f32x4 o3 = reinterpret_cast<const f32x4*>(part3)[fq];
        reinterpret_cast<f32x4*>(colvS)[fq] = a3 + o3;
        const f32x4 rw = a2 + o2;
        const f32x4 dg = a1 + o1;
        const int d4 = fq << 2;
        rwS[d4 + 0] = rw.x + base;
        rwS[d4 + 1] = rw.y + base;
        rwS[d4 + 2] = rw.z + base;
        rwS[d4 + 3] = rw.w + base;
        dgS[d4 + 0] = dg.x + y4;
        dgS[d4 + 1] = dg.y + y4;
        dgS[d4 + 2] = dg.z + y4;
        dgS[d4 + 3] = dg.w + y4;
    }
    __syncthreads();

    // ---- store phase: contiguous 512 KB ascending stream per block ----
    const int   c4    = t & 127;
    const f32x4 cv    = reinterpret_cast<const f32x4*>(colvS)[c4];
    const int   cbase = c4 << 2;               // column of res.x
    const int   rbase = half_img * ROWS;
    const int   out_base = bo * (ND * (ND / 4)) + rbase * (ND / 4);

    #pragma unroll 8
    for (int k = 0; k < ROWS / 2; ++k) {       // 128 iterations, 2 rows each
        const int rl = (k << 1) + half;        // 0..255, wave-uniform
        const int r  = rbase + rl;
        const float rv = rwS[r];               // LDS broadcast
        const float dv = dgS[r];               // LDS broadcast
        const int dcol = r - cbase;            // in [0,3] iff diag in this float4
        f32x4 res;
        res.x = rv + cv.x + ((dcol == 0) ? dv : 0.0f);
        res.y = rv + cv.y + ((dcol == 1) ? dv : 0.0f);
        res.z = rv + cv.z + ((dcol == 2) ? dv : 0.0f);
        res.w = rv + cv.w + ((dcol == 3) ? dv : 0.0f);
        out[out_base + (rl << 7) + c4] = res;
    }
}

extern "C" void kernel_launch(void* const* d_in, const int* in_sizes, int n_in,
                              void* d_out, int out_size, void* d_ws, size_t ws_size,
                              hipStream_t stream) {
    const float* x      = (const float*)d_in[0];
    const float* weight = (const float*)d_in[1];
    const float* bias   = (const float*)d_in[2];

    leq_fused<<<NB * NO * RT, 256, 0, stream>>>(x, weight, bias, (f32x4*)d_out);
}